// Round 1
// baseline (193.887 us; speedup 1.0000x reference)
//
#include <hip/hip_runtime.h>
#include <math.h>

typedef _Float16 half8 __attribute__((ext_vector_type(8)));
typedef float floatx4 __attribute__((ext_vector_type(4)));

#define C_RADIUS 20.0f

// ---------------------------------------------------------------------------
// d_ws layout (units = _Float16):
//   W1f [28 tn][64 lane][8]        @ 0       L1 weights: n=tn*16+(l&15), k=8*(l>>4)+e
//                                            k<17 -> w1[n][k], k==17 -> b1[n], else 0; n>=400 -> 0
//   W2f [20 tn][13 ks][64][8]      @ 14336   k=32*ks+8*(l>>4)+e; k<400 -> w2[n][k], k==400 -> b2[n]
//   W3f [10 ks][64][8]             @ 147456  n=l&15(<6); k<300 -> w3[n][k], k==300 -> b3[n]
// ---------------------------------------------------------------------------

__global__ void actor_prep(const float* __restrict__ w1, const float* __restrict__ b1,
                           const float* __restrict__ w2, const float* __restrict__ b2,
                           const float* __restrict__ w3, const float* __restrict__ b3,
                           _Float16* __restrict__ ws) {
  int gid = blockIdx.x * 256 + threadIdx.x;
  if (gid >= 19072) return;
  half8 hv;
  _Float16* dst;
  if (gid < 1792) {  // W1f
    int l = gid & 63, tn = gid >> 6;
    int n = tn * 16 + (l & 15);
    int kc = 8 * (l >> 4);
#pragma unroll
    for (int e = 0; e < 8; ++e) {
      int k = kc + e;
      float v = 0.f;
      if (n < 400) {
        if (k < 17) v = w1[n * 17 + k];
        else if (k == 17) v = b1[n];
      }
      hv[e] = (_Float16)v;
    }
    dst = ws + gid * 8;
  } else if (gid < 1792 + 16640) {  // W2f
    int g = gid - 1792;
    int l = g & 63, t = g >> 6;     // t = tn*13 + ks
    int ks = t % 13, tn = t / 13;
    int n = tn * 16 + (l & 15);
    int kc = ks * 32 + 8 * (l >> 4);
#pragma unroll
    for (int e = 0; e < 8; ++e) {
      int k = kc + e;
      float v = 0.f;
      if (n < 300) {
        if (k < 400) v = w2[n * 400 + k];
        else if (k == 400) v = b2[n];
      }
      hv[e] = (_Float16)v;
    }
    dst = ws + 14336 + g * 8;
  } else {  // W3f
    int g = gid - 1792 - 16640;
    int l = g & 63, ks = g >> 6;
    int n = l & 15;
    int kc = ks * 32 + 8 * (l >> 4);
#pragma unroll
    for (int e = 0; e < 8; ++e) {
      int k = kc + e;
      float v = 0.f;
      if (n < 6) {
        if (k < 300) v = w3[n * 300 + k];
        else if (k == 300) v = b3[n];
      }
      hv[e] = (_Float16)v;
    }
    dst = ws + 147456 + g * 8;
  }
  *reinterpret_cast<half8*>(dst) = hv;
}

// LDS fragment addressing: activation tile stored as [ks][row][chunk-slot][8 f16],
// 16B unit index; chunk-slot = chunk ^ ((row>>1)&3) to spread banks on ds_read_b128.
static __device__ __forceinline__ int a_slot(int ks, int row, int ch) {
  return (ks * 64 + row) * 4 + (ch ^ ((row >> 1) & 3));
}

__global__ __launch_bounds__(256) void actor_fused(const float* __restrict__ state,
                                                   const _Float16* __restrict__ ws,
                                                   float* __restrict__ out) {
  __shared__ __align__(16) _Float16 a1L[13 * 64 * 32];  // K=416 (400 + bias@400 + pad), 52KB
  __shared__ __align__(16) _Float16 a2L[10 * 64 * 32];  // K=320 (300 + bias@300 + pad), 40KB
  __shared__ float stateL[64 * 18];
  __shared__ float z3L[64 * 8];

  const int tid = threadIdx.x;
  const int lane = tid & 63;
  const int w = tid >> 6;
  const int r15 = lane & 15;
  const int c4 = lane >> 4;
  const int row0 = blockIdx.x * 64;

  // ---- stage 0: state -> LDS; init a1 K-pad region (col 400 = 1.0 bias slot) ----
  for (int i = tid; i < 64 * 17; i += 256) {
    int r = i / 17;
    int c = i - r * 17;
    stateL[r * 18 + c] = state[row0 * 17 + i];
  }
  for (int i = tid; i < 2048; i += 256) {
    int row = i >> 5;
    int j = i & 31;
    int j0 = (2 ^ ((row >> 1) & 3)) * 8;  // physical slot of logical chunk 2, elem 0 -> k=400
    a1L[12 * 64 * 32 + i] = (j == j0) ? (_Float16)1.0f : (_Float16)0.0f;
  }
  __syncthreads();

  // ---- phase 1: a1 = relu(state @ W1^T + b1)  (waves split the 28 n-tiles) ----
  {
    half8 aF[4];
#pragma unroll
    for (int m = 0; m < 4; ++m) {
      half8 v;
#pragma unroll
      for (int e = 0; e < 8; ++e) {
        int k = 8 * c4 + e;
        float x = 0.f;
        if (k < 17) x = stateL[(16 * m + r15) * 18 + k];
        else if (k == 17) x = 1.0f;  // bias slot
        v[e] = (_Float16)x;
      }
      aF[m] = v;
    }
    const half8* W1f = reinterpret_cast<const half8*>(ws);
    for (int t = 0; t < 7; ++t) {
      int tn = w * 7 + t;
      half8 bF = W1f[tn * 64 + lane];
      floatx4 acc[4];
#pragma unroll
      for (int m = 0; m < 4; ++m)
        acc[m] = __builtin_amdgcn_mfma_f32_16x16x32_f16(aF[m], bF, (floatx4){0.f, 0.f, 0.f, 0.f}, 0, 0, 0);
      int col = tn * 16 + r15;
      if (col < 400) {  // tiles 25..27 are zero-pad, skip store
        int ks = col >> 5, ch = (col >> 3) & 3, e = col & 7;
#pragma unroll
        for (int m = 0; m < 4; ++m)
#pragma unroll
          for (int r = 0; r < 4; ++r) {
            int row = 16 * m + 4 * c4 + r;
            float v = acc[m][r];
            v = v > 0.f ? v : 0.f;
            a1L[a_slot(ks, row, ch) * 8 + e] = (_Float16)v;
          }
      }
    }
  }
  __syncthreads();

  // ---- phase 2: a2 = relu(a1 @ W2^T + b2)  (waves split 20 n-tiles -> W2f read ONCE/block) ----
  {
    const half8* W2f = reinterpret_cast<const half8*>(ws + 14336);
    const int tn0 = w * 5;
    floatx4 acc[4][5];
#pragma unroll
    for (int m = 0; m < 4; ++m)
#pragma unroll
      for (int j = 0; j < 5; ++j) acc[m][j] = (floatx4){0.f, 0.f, 0.f, 0.f};
#pragma unroll 2
    for (int ks = 0; ks < 13; ++ks) {
      half8 aF[4];
#pragma unroll
      for (int m = 0; m < 4; ++m) {
        int row = 16 * m + r15;
        aF[m] = *reinterpret_cast<const half8*>(&a1L[a_slot(ks, row, c4) * 8]);
      }
      half8 bF[5];
#pragma unroll
      for (int j = 0; j < 5; ++j) bF[j] = W2f[((tn0 + j) * 13 + ks) * 64 + lane];
#pragma unroll
      for (int j = 0; j < 5; ++j)
#pragma unroll
        for (int m = 0; m < 4; ++m)
          acc[m][j] = __builtin_amdgcn_mfma_f32_16x16x32_f16(aF[m], bF[j], acc[m][j], 0, 0, 0);
    }
    // epilogue: relu; col 300 forced to 1.0 (bias slot for L3); tile 19 writes zero pad 304..319
#pragma unroll
    for (int j = 0; j < 5; ++j) {
      int col = (tn0 + j) * 16 + r15;
      int ks2 = col >> 5, ch = (col >> 3) & 3, e = col & 7;
#pragma unroll
      for (int m = 0; m < 4; ++m)
#pragma unroll
        for (int r = 0; r < 4; ++r) {
          int row = 16 * m + 4 * c4 + r;
          float v = acc[m][j][r];
          v = v > 0.f ? v : 0.f;
          if (col == 300) v = 1.0f;
          a2L[a_slot(ks2, row, ch) * 8 + e] = (_Float16)v;
        }
    }
  }
  __syncthreads();

  // ---- phase 3: z3 = a2 @ W3^T + b3, tanh  (waves split m-tiles) ----
  {
    const half8* W3f = reinterpret_cast<const half8*>(ws + 147456);
    floatx4 accA = (floatx4){0.f, 0.f, 0.f, 0.f};
    floatx4 accB = (floatx4){0.f, 0.f, 0.f, 0.f};
    int row = 16 * w + r15;
#pragma unroll
    for (int ks = 0; ks < 10; ks += 2) {
      half8 f0 = *reinterpret_cast<const half8*>(&a2L[a_slot(ks, row, c4) * 8]);
      half8 f1 = *reinterpret_cast<const half8*>(&a2L[a_slot(ks + 1, row, c4) * 8]);
      accA = __builtin_amdgcn_mfma_f32_16x16x32_f16(f0, W3f[ks * 64 + lane], accA, 0, 0, 0);
      accB = __builtin_amdgcn_mfma_f32_16x16x32_f16(f1, W3f[(ks + 1) * 64 + lane], accB, 0, 0, 0);
    }
    floatx4 z = accA + accB;
    if (r15 < 6) {
#pragma unroll
      for (int r = 0; r < 4; ++r) {
        int orow = 16 * w + 4 * c4 + r;
        z3L[orow * 8 + r15] = tanhf(z[r]);
      }
    }
  }
  __syncthreads();

  // ---- phase 4: weighted-L1-ball projection (per row, D=6), threads 0..63 ----
  if (tid < 64) {
    const int row = tid;
    float q[6], wv[6], aq[6], wa[6];
    float S = 0.f;
#pragma unroll
    for (int i = 0; i < 6; ++i) {
      q[i] = z3L[row * 8 + i];
      wv[i] = fabsf(stateL[row * 18 + 11 + i]);
      aq[i] = fabsf(q[i]);
      wa[i] = wv[i] * aq[i];
      S += wa[i];
    }
    float lam = 0.f;
    if (!(S <= C_RADIUS)) {
      float rr[6], w2s[6], was[6];
#pragma unroll
      for (int i = 0; i < 6; ++i) {
        rr[i] = (wv[i] > 0.f) ? (aq[i] / fmaxf(wv[i], 1e-30f)) : -__builtin_inff();
        w2s[i] = wv[i] * wv[i];
        was[i] = wa[i];
      }
      // descending bubble sort, fully unrolled (constant indices -> registers)
#pragma unroll
      for (int p = 0; p < 5; ++p)
#pragma unroll
        for (int j2 = 0; j2 < 5; ++j2)
          if (j2 < 5 - p) {
            if (rr[j2] < rr[j2 + 1]) {
              float t0 = rr[j2];  rr[j2] = rr[j2 + 1];  rr[j2 + 1] = t0;
              float t1 = w2s[j2]; w2s[j2] = w2s[j2 + 1]; w2s[j2 + 1] = t1;
              float t2 = was[j2]; was[j2] = was[j2 + 1]; was[j2 + 1] = t2;
            }
          }
      float A = 0.f, Bc = 0.f;
      float lamk[6];
      int kc = 0;
#pragma unroll
      for (int i = 0; i < 6; ++i) {
        A += was[i];
        Bc += w2s[i];
        lamk[i] = (A - C_RADIUS) / fmaxf(Bc, 1e-30f);
        if (rr[i] > lamk[i]) ++kc;
      }
      int idx = kc - 1;
      if (idx < 0) idx = 0;
      float lsel = lamk[0];
#pragma unroll
      for (int i = 1; i < 6; ++i)
        if (i == idx) lsel = lamk[i];
      lam = fmaxf(lsel, 0.f);
    }
    const int gbase = (row0 + row) * 6;
#pragma unroll
    for (int i = 0; i < 6; ++i) {
      float x = fmaxf(aq[i] - lam * wv[i], 0.f);
      out[gbase + i] = copysignf(x, q[i]);
    }
  }
}

extern "C" void kernel_launch(void* const* d_in, const int* in_sizes, int n_in,
                              void* d_out, int out_size, void* d_ws, size_t ws_size,
                              hipStream_t stream) {
  const float* state = (const float*)d_in[0];
  const float* w1 = (const float*)d_in[1];
  const float* b1 = (const float*)d_in[2];
  const float* w2 = (const float*)d_in[3];
  const float* b2 = (const float*)d_in[4];
  const float* w3 = (const float*)d_in[5];
  const float* b3 = (const float*)d_in[6];
  _Float16* ws = (_Float16*)d_ws;
  float* out = (float*)d_out;

  actor_prep<<<75, 256, 0, stream>>>(w1, b1, w2, b2, w3, b3, ws);
  actor_fused<<<4096, 256, 0, stream>>>(state, ws, out);
}

// Round 2
// 111.334 us; speedup vs baseline: 1.7415x; 1.7415x over previous
//
#include <hip/hip_runtime.h>
#include <math.h>

typedef _Float16 half8 __attribute__((ext_vector_type(8)));
typedef float floatx4 __attribute__((ext_vector_type(4)));

#define C_RADIUS 20.0f

// ---------------------------------------------------------------------------
// d_ws layout (units = _Float16):
//   W1f [28 tn][64 lane][8]        @ 0       L1: n=tn*16+(l&15), k=8*(l>>4)+e
//                                            k<17 -> w1[n][k], k==17 -> b1[n], else 0; n>=400 -> 0
//   W2f [20 tn][13 ks][64][8]      @ 14336   k=32*ks+8*(l>>4)+e; k<400 -> w2[n][k], k==400 -> b2[n]
//   W3f [10 ks][64][8]             @ 147456  n=l&15(<6); k<300 -> w3[n][k], k==300 -> b3[n]
// ---------------------------------------------------------------------------

__global__ void actor_prep(const float* __restrict__ w1, const float* __restrict__ b1,
                           const float* __restrict__ w2, const float* __restrict__ b2,
                           const float* __restrict__ w3, const float* __restrict__ b3,
                           _Float16* __restrict__ ws) {
  int gid = blockIdx.x * 256 + threadIdx.x;
  if (gid >= 19072) return;
  half8 hv;
  _Float16* dst;
  if (gid < 1792) {  // W1f
    int l = gid & 63, tn = gid >> 6;
    int n = tn * 16 + (l & 15);
    int kc = 8 * (l >> 4);
#pragma unroll
    for (int e = 0; e < 8; ++e) {
      int k = kc + e;
      float v = 0.f;
      if (n < 400) {
        if (k < 17) v = w1[n * 17 + k];
        else if (k == 17) v = b1[n];
      }
      hv[e] = (_Float16)v;
    }
    dst = ws + gid * 8;
  } else if (gid < 1792 + 16640) {  // W2f
    int g = gid - 1792;
    int l = g & 63, t = g >> 6;     // t = tn*13 + ks
    int ks = t % 13, tn = t / 13;
    int n = tn * 16 + (l & 15);
    int kc = ks * 32 + 8 * (l >> 4);
#pragma unroll
    for (int e = 0; e < 8; ++e) {
      int k = kc + e;
      float v = 0.f;
      if (n < 300) {
        if (k < 400) v = w2[n * 400 + k];
        else if (k == 400) v = b2[n];
      }
      hv[e] = (_Float16)v;
    }
    dst = ws + 14336 + g * 8;
  } else {  // W3f
    int g = gid - 1792 - 16640;
    int l = g & 63, ks = g >> 6;
    int n = l & 15;
    int kc = ks * 32 + 8 * (l >> 4);
#pragma unroll
    for (int e = 0; e < 8; ++e) {
      int k = kc + e;
      float v = 0.f;
      if (n < 6) {
        if (k < 300) v = w3[n * 300 + k];
        else if (k == 300) v = b3[n];
      }
      hv[e] = (_Float16)v;
    }
    dst = ws + 147456 + g * 8;
  }
  *reinterpret_cast<half8*>(dst) = hv;
}

// LDS fragment addressing: activation tile stored as [ks][row][chunk-slot][8 f16],
// 16B unit index; chunk-slot = chunk ^ ((row>>1)&3) to spread banks on ds_read_b128.
static __device__ __forceinline__ int a_slot(int ks, int row, int ch) {
  return (ks * 64 + row) * 4 + (ch ^ ((row >> 1) & 3));
}

__global__ __launch_bounds__(512, 4) void actor_fused(const float* __restrict__ state,
                                                      const _Float16* __restrict__ ws,
                                                      float* __restrict__ out) {
  // aL serves BOTH a1 (13 ks-slots, K=416) and, after phase 2, a2 (10 ks-slots, K=320).
  __shared__ __align__(16) _Float16 aL[13 * 64 * 32];   // 52 KB
  __shared__ float stateL[64 * 18];                     // 4.5 KB
  __shared__ float z3L[64 * 8];                         // 2 KB
  __shared__ __align__(16) float outL[64 * 6];          // 1.5 KB

  const int tid = threadIdx.x;
  const int lane = tid & 63;
  const int w = tid >> 6;           // 8 waves
  const int r15 = lane & 15;
  const int c4 = lane >> 4;
  const int row0 = blockIdx.x * 64;

  // ---- stage 0: state -> LDS; init a1 ks=12 region (col 400 = 1.0 bias slot) ----
  for (int i = tid; i < 64 * 17; i += 512) {
    int r = i / 17;
    int c = i - r * 17;
    stateL[r * 18 + c] = state[row0 * 17 + i];
  }
  for (int i = tid; i < 2048; i += 512) {
    int row = i >> 5;
    int j = i & 31;
    int j0 = (2 ^ ((row >> 1) & 3)) * 8;  // physical slot of logical chunk 2, elem 0 -> k=400
    aL[12 * 64 * 32 + i] = (j == j0) ? (_Float16)1.0f : (_Float16)0.0f;
  }
  __syncthreads();

  // ---- phase 1: a1 = relu(state @ W1^T + b1); 25 n-tiles over 8 waves ----
  {
    half8 aF[4];
#pragma unroll
    for (int m = 0; m < 4; ++m) {
      half8 v;
#pragma unroll
      for (int e = 0; e < 8; ++e) {
        int k = 8 * c4 + e;
        float x = 0.f;
        if (k < 17) x = stateL[(16 * m + r15) * 18 + k];
        else if (k == 17) x = 1.0f;  // bias slot
        v[e] = (_Float16)x;
      }
      aF[m] = v;
    }
    const half8* W1f = reinterpret_cast<const half8*>(ws);
#pragma unroll
    for (int t = 0; t < 4; ++t) {
      int tn = w + 8 * t;
      if (tn < 25) {
        half8 bF = W1f[tn * 64 + lane];
        floatx4 acc[4];
#pragma unroll
        for (int m = 0; m < 4; ++m)
          acc[m] = __builtin_amdgcn_mfma_f32_16x16x32_f16(aF[m], bF, (floatx4){0.f, 0.f, 0.f, 0.f}, 0, 0, 0);
        int col = tn * 16 + r15;  // always < 400 for tn<25
        int ks = col >> 5, ch = (col >> 3) & 3, e = col & 7;
#pragma unroll
        for (int m = 0; m < 4; ++m)
#pragma unroll
          for (int r = 0; r < 4; ++r) {
            int row = 16 * m + 4 * c4 + r;
            float v = acc[m][r];
            v = v > 0.f ? v : 0.f;
            aL[a_slot(ks, row, ch) * 8 + e] = (_Float16)v;
          }
      }
    }
  }
  __syncthreads();

  // ---- phase 2: a2 = relu(a1 @ W2^T + b2); 20 n-tiles split {3,3,3,3,2,2,2,2} ----
  {
    const half8* W2f = reinterpret_cast<const half8*>(ws + 14336);
    const int nt = (w < 4) ? 3 : 2;
    const int tn0 = (w < 4) ? (w * 3) : (12 + (w - 4) * 2);
    floatx4 acc[4][3];
#pragma unroll
    for (int m = 0; m < 4; ++m)
#pragma unroll
      for (int t = 0; t < 3; ++t) acc[m][t] = (floatx4){0.f, 0.f, 0.f, 0.f};

    half8 bF[3], bFn[3];
#pragma unroll
    for (int t = 0; t < 3; ++t)
      if (t < nt) bF[t] = W2f[((tn0 + t) * 13 + 0) * 64 + lane];

#pragma unroll 1
    for (int ks = 0; ks < 13; ++ks) {
      if (ks + 1 < 13) {
#pragma unroll
        for (int t = 0; t < 3; ++t)
          if (t < nt) bFn[t] = W2f[((tn0 + t) * 13 + ks + 1) * 64 + lane];
      }
      half8 aF[4];
#pragma unroll
      for (int m = 0; m < 4; ++m)
        aF[m] = *reinterpret_cast<const half8*>(&aL[a_slot(ks, 16 * m + r15, c4) * 8]);
#pragma unroll
      for (int t = 0; t < 3; ++t)
        if (t < nt)
#pragma unroll
          for (int m = 0; m < 4; ++m)
            acc[m][t] = __builtin_amdgcn_mfma_f32_16x16x32_f16(aF[m], bF[t], acc[m][t], 0, 0, 0);
#pragma unroll
      for (int t = 0; t < 3; ++t) bF[t] = bFn[t];
    }
    __syncthreads();  // all a1 reads complete before aliased a2 writes

    // epilogue: relu; col 300 forced to 1.0 (bias slot for L3); cols>=304 are zero pad
#pragma unroll
    for (int t = 0; t < 3; ++t)
      if (t < nt) {
        int col = (tn0 + t) * 16 + r15;
        int ks2 = col >> 5, ch = (col >> 3) & 3, e = col & 7;
#pragma unroll
        for (int m = 0; m < 4; ++m)
#pragma unroll
          for (int r = 0; r < 4; ++r) {
            int row = 16 * m + 4 * c4 + r;
            float v = acc[m][t][r];
            v = v > 0.f ? v : 0.f;
            if (col == 300) v = 1.0f;
            aL[a_slot(ks2, row, ch) * 8 + e] = (_Float16)v;
          }
      }
  }
  __syncthreads();

  // ---- phase 3: z3 = a2 @ W3^T + b3, tanh; waves 0..3 (one 16-row m-tile each) ----
  if (w < 4) {
    const half8* W3f = reinterpret_cast<const half8*>(ws + 147456);
    floatx4 accA = (floatx4){0.f, 0.f, 0.f, 0.f};
    floatx4 accB = (floatx4){0.f, 0.f, 0.f, 0.f};
    int row = 16 * w + r15;
#pragma unroll
    for (int ks = 0; ks < 10; ks += 2) {
      half8 f0 = *reinterpret_cast<const half8*>(&aL[a_slot(ks, row, c4) * 8]);
      half8 f1 = *reinterpret_cast<const half8*>(&aL[a_slot(ks + 1, row, c4) * 8]);
      accA = __builtin_amdgcn_mfma_f32_16x16x32_f16(f0, W3f[ks * 64 + lane], accA, 0, 0, 0);
      accB = __builtin_amdgcn_mfma_f32_16x16x32_f16(f1, W3f[(ks + 1) * 64 + lane], accB, 0, 0, 0);
    }
    floatx4 z = accA + accB;
    if (r15 < 6) {
#pragma unroll
      for (int r = 0; r < 4; ++r) {
        int orow = 16 * w + 4 * c4 + r;
        z3L[orow * 8 + r15] = tanhf(z[r]);
      }
    }
  }
  __syncthreads();

  // ---- phase 4: weighted-L1-ball projection (per row, D=6), threads 0..63 ----
  if (tid < 64) {
    const int row = tid;
    float q[6], wv[6], aq[6], wa[6];
    float S = 0.f;
#pragma unroll
    for (int i = 0; i < 6; ++i) {
      q[i] = z3L[row * 8 + i];
      wv[i] = fabsf(stateL[row * 18 + 11 + i]);
      aq[i] = fabsf(q[i]);
      wa[i] = wv[i] * aq[i];
      S += wa[i];
    }
    float lam = 0.f;
    if (!(S <= C_RADIUS)) {
      float rr[6], w2s[6], was[6];
#pragma unroll
      for (int i = 0; i < 6; ++i) {
        rr[i] = (wv[i] > 0.f) ? (aq[i] / fmaxf(wv[i], 1e-30f)) : -__builtin_inff();
        w2s[i] = wv[i] * wv[i];
        was[i] = wa[i];
      }
#pragma unroll
      for (int p = 0; p < 5; ++p)
#pragma unroll
        for (int j2 = 0; j2 < 5; ++j2)
          if (j2 < 5 - p) {
            if (rr[j2] < rr[j2 + 1]) {
              float t0 = rr[j2];  rr[j2] = rr[j2 + 1];  rr[j2 + 1] = t0;
              float t1 = w2s[j2]; w2s[j2] = w2s[j2 + 1]; w2s[j2 + 1] = t1;
              float t2 = was[j2]; was[j2] = was[j2 + 1]; was[j2 + 1] = t2;
            }
          }
      float A = 0.f, Bc = 0.f;
      float lamk[6];
      int kc = 0;
#pragma unroll
      for (int i = 0; i < 6; ++i) {
        A += was[i];
        Bc += w2s[i];
        lamk[i] = (A - C_RADIUS) / fmaxf(Bc, 1e-30f);
        if (rr[i] > lamk[i]) ++kc;
      }
      int idx = kc - 1;
      if (idx < 0) idx = 0;
      float lsel = lamk[0];
#pragma unroll
      for (int i = 1; i < 6; ++i)
        if (i == idx) lsel = lamk[i];
      lam = fmaxf(lsel, 0.f);
    }
#pragma unroll
    for (int i = 0; i < 6; ++i) {
      float x = fmaxf(aq[i] - lam * wv[i], 0.f);
      outL[row * 6 + i] = copysignf(x, q[i]);
    }
  }
  __syncthreads();

  // coalesced float4 store of the 384-float output tile
  if (tid < 96) {
    float4 v = reinterpret_cast<const float4*>(outL)[tid];
    reinterpret_cast<float4*>(out)[blockIdx.x * 96 + tid] = v;
  }
}

extern "C" void kernel_launch(void* const* d_in, const int* in_sizes, int n_in,
                              void* d_out, int out_size, void* d_ws, size_t ws_size,
                              hipStream_t stream) {
  const float* state = (const float*)d_in[0];
  const float* w1 = (const float*)d_in[1];
  const float* b1 = (const float*)d_in[2];
  const float* w2 = (const float*)d_in[3];
  const float* b2 = (const float*)d_in[4];
  const float* w3 = (const float*)d_in[5];
  const float* b3 = (const float*)d_in[6];
  _Float16* ws = (_Float16*)d_ws;
  float* out = (float*)d_out;

  actor_prep<<<75, 256, 0, stream>>>(w1, b1, w2, b2, w3, b3, ws);
  actor_fused<<<4096, 512, 0, stream>>>(state, ws, out);
}

// Round 4
// 110.221 us; speedup vs baseline: 1.7591x; 1.0101x over previous
//
#include <hip/hip_runtime.h>
#include <math.h>

typedef _Float16 half2v __attribute__((ext_vector_type(2)));
typedef __fp16 fp16x2 __attribute__((ext_vector_type(2)));
typedef _Float16 half4 __attribute__((ext_vector_type(4)));
typedef _Float16 half8 __attribute__((ext_vector_type(8)));
typedef float floatx4 __attribute__((ext_vector_type(4)));

#define C_RADIUS 20.0f

// ---------------------------------------------------------------------------
// d_ws layout (units = _Float16). Weight fragments for mfma_f32_16x16x16_f16:
// per half8 element e' (0..7): p = e'>>2, k_local = 4*(lane>>4) + (e'&3).
//   W1f [25+3 tn][64 lane][8]      @ 0       k = 16p + k_local
//   W2f [20 tn][13 ks][64][8]      @ 14336   k = 32ks + 16p + k_local
//   W3f [10 ks][64][8]             @ 147456  n = lane&15 (<6)
// ---------------------------------------------------------------------------

__global__ void actor_prep(const float* __restrict__ w1, const float* __restrict__ b1,
                           const float* __restrict__ w2, const float* __restrict__ b2,
                           const float* __restrict__ w3, const float* __restrict__ b3,
                           _Float16* __restrict__ ws) {
  int gid = blockIdx.x * 256 + threadIdx.x;
  if (gid >= 19072) return;
  half8 hv;
  _Float16* dst;
  if (gid < 1792) {  // W1f
    int l = gid & 63, tn = gid >> 6;
    int n = tn * 16 + (l & 15);
#pragma unroll
    for (int e = 0; e < 8; ++e) {
      int k = 16 * (e >> 2) + 4 * (l >> 4) + (e & 3);
      float v = 0.f;
      if (n < 400) {
        if (k < 17) v = w1[n * 17 + k];
        else if (k == 17) v = b1[n];
      }
      hv[e] = (_Float16)v;
    }
    dst = ws + gid * 8;
  } else if (gid < 1792 + 16640) {  // W2f
    int g = gid - 1792;
    int l = g & 63, t = g >> 6;     // t = tn*13 + ks
    int ks = t % 13, tn = t / 13;
    int n = tn * 16 + (l & 15);
#pragma unroll
    for (int e = 0; e < 8; ++e) {
      int k = 32 * ks + 16 * (e >> 2) + 4 * (l >> 4) + (e & 3);
      float v = 0.f;
      if (n < 300) {
        if (k < 400) v = w2[n * 400 + k];
        else if (k == 400) v = b2[n];
      }
      hv[e] = (_Float16)v;
    }
    dst = ws + 14336 + g * 8;
  } else {  // W3f
    int g = gid - 1792 - 16640;
    int l = g & 63, ks = g >> 6;
    int n = l & 15;
#pragma unroll
    for (int e = 0; e < 8; ++e) {
      int k = 32 * ks + 16 * (e >> 2) + 4 * (l >> 4) + (e & 3);
      float v = 0.f;
      if (n < 6) {
        if (k < 300) v = w3[n * 300 + k];
        else if (k == 300) v = b3[n];
      }
      hv[e] = (_Float16)v;
    }
    dst = ws + 147456 + g * 8;
  }
  *reinterpret_cast<half8*>(dst) = hv;
}

// Activation LDS layout: 4col x 16row subtiles ("blocks", 128 B each):
//   elem(row,col) = (kb*4 + rb)*64 + c_in*16 + r_in,  kb=col>>2, c_in=col&3,
//   rb=row>>4, r_in=row&15.
// tr-read of A-frag (mt, ks32, p): byte addr = ((8ks+4p+c4)*4+mt)*128 + r15*8
//   -> delivers col r15's 4 elems (k = 32ks+16p+4c4+{0..3}) = one 16x16x16 A-op.

#define TRD(dst, addr, OFF) \
  asm volatile("ds_read_b64_tr_b16 %0, %1 offset:" OFF : "=v"(dst) : "v"(addr))

#define ISSUE_A(buf, addr)                                   \
  do {                                                       \
    TRD(buf[0], addr, "0");    TRD(buf[1], addr, "128");     \
    TRD(buf[2], addr, "256");  TRD(buf[3], addr, "384");     \
    TRD(buf[4], addr, "2048"); TRD(buf[5], addr, "2176");    \
    TRD(buf[6], addr, "2304"); TRD(buf[7], addr, "2432");    \
  } while (0)

#define LGKM(N)                                              \
  do {                                                       \
    asm volatile("s_waitcnt lgkmcnt(" #N ")" ::: "memory");  \
    __builtin_amdgcn_sched_barrier(0);                       \
  } while (0)

#define LO4(x) __builtin_shufflevector(x, x, 0, 1, 2, 3)
#define HI4(x) __builtin_shufflevector(x, x, 4, 5, 6, 7)
#define MFMA16(A, B, C) C = __builtin_amdgcn_mfma_f32_16x16x16f16(A, B, C, 0, 0, 0)

// pack 4 floats -> half4 via two v_cvt_pkrtz_f16_f32 (bit-cast __fp16x2 -> _Float16x2)
__device__ __forceinline__ half4 pack4(float v0, float v1, float v2, float v3) {
  fp16x2 a = __builtin_amdgcn_cvt_pkrtz(v0, v1);
  fp16x2 b = __builtin_amdgcn_cvt_pkrtz(v2, v3);
  half2v a2 = __builtin_bit_cast(half2v, a);
  half2v b2 = __builtin_bit_cast(half2v, b);
  return __builtin_shufflevector(a2, b2, 0, 1, 2, 3);
}

__device__ __forceinline__ float fast_tanh(float x) {
  float e = __expf(2.0f * x);
  return 1.0f - 2.0f / (e + 1.0f);
}

__global__ __launch_bounds__(512, 4) void actor_fused(const float* __restrict__ state,
                                                      const _Float16* __restrict__ ws,
                                                      float* __restrict__ out) {
  // a1: 416 cols (400 + bias col 400 + zero pad) x 64 rows = 416 blocks. 52 KB.
  // a2 (320 cols, 320 blocks) aliases the same buffer after a barrier.
  __shared__ __align__(128) _Float16 aL[26624];
  __shared__ __align__(128) _Float16 stateF[2048];  // 32 cols x 64 rows, 4 KB
  __shared__ float z3L[64 * 8];
  __shared__ __align__(16) float outL[64 * 6];
  __shared__ float wvL[64 * 6];

  const int tid = threadIdx.x;
  const int lane = tid & 63;
  const int w = tid >> 6;       // 8 waves
  const int r15 = lane & 15;
  const int c4 = lane >> 4;
  const int row0 = blockIdx.x * 64;

  const unsigned aBase = (unsigned)(size_t)(&aL[0]);
  const unsigned sBase = (unsigned)(size_t)(&stateF[0]);

  // ---- stage 0: stateF (cols 0..16 state, 17 = 1.0 bias, 18..31 = 0);
  //      a1 bias region (col 400 = 1.0, 401..415 = 0); wvL ----
  for (int i = tid; i < 1024; i += 512) {
    int blk = i >> 5, q = i & 31, ci = q >> 3, s = q & 7;
    int kb = blk >> 2, rb = blk & 3;
    int row = rb * 16 + 2 * s, col = kb * 4 + ci;
    float v0 = 0.f, v1 = 0.f;
    if (col < 17) {
      v0 = state[(row0 + row) * 17 + col];
      v1 = state[(row0 + row + 1) * 17 + col];
    } else if (col == 17) {
      v0 = 1.f; v1 = 1.f;
    }
    half2v h = {(_Float16)v0, (_Float16)v1};
    *reinterpret_cast<half2v*>(reinterpret_cast<char*>(stateF) + blk * 128 + ci * 32 + 4 * s) = h;
  }
  for (int i = tid; i < 1024; i += 512)
    aL[25600 + i] = (i < 256 && (i & 63) < 16) ? (_Float16)1.0f : (_Float16)0.0f;
  if (tid < 384) {
    int r = tid / 6, c = tid - r * 6;
    wvL[tid] = fabsf(state[(row0 + r) * 17 + 11 + c]);
  }
  __syncthreads();

  // ---- phase 1: a1 = relu(state @ W1^T + b1); 25 n-tiles over 8 waves ----
  {
    half4 S[8];
    unsigned sA = sBase + c4 * 512 + r15 * 8;
    ISSUE_A(S, sA);
    LGKM(0);
    const half8* W1f = reinterpret_cast<const half8*>(ws);
#pragma unroll
    for (int t = 0; t < 4; ++t) {
      int tn = w + 8 * t;
      if (tn < 25) {
        half8 bw = W1f[tn * 64 + lane];
        half4 blo = LO4(bw), bhi = HI4(bw);
        floatx4 acc[4];
#pragma unroll
        for (int m = 0; m < 4; ++m) {
          acc[m] = (floatx4){0.f, 0.f, 0.f, 0.f};
          MFMA16(S[m], blo, acc[m]);
          MFMA16(S[4 + m], bhi, acc[m]);
        }
        int col = tn * 16 + r15;  // < 400
        int wrel = ((col >> 2) * 4) * 128 + (col & 3) * 32 + 8 * c4;
#pragma unroll
        for (int m = 0; m < 4; ++m) {
          half4 hv = pack4(fmaxf(acc[m][0], 0.f), fmaxf(acc[m][1], 0.f),
                           fmaxf(acc[m][2], 0.f), fmaxf(acc[m][3], 0.f));
          *reinterpret_cast<half4*>(reinterpret_cast<char*>(aL) + wrel + m * 128) = hv;
        }
      }
    }
  }
  __syncthreads();

  // ---- phase 2: a2 = relu(a1 @ W2^T + b2); n-tiles {3,3,3,3,2,2,2,2} ----
  {
    const half8* W2f = reinterpret_cast<const half8*>(ws + 14336);
    const int nt = (w < 4) ? 3 : 2;
    const int tn0 = (w < 4) ? (w * 3) : (12 + (w - 4) * 2);
    floatx4 acc[4][3];
#pragma unroll
    for (int m = 0; m < 4; ++m)
#pragma unroll
      for (int t = 0; t < 3; ++t) acc[m][t] = (floatx4){0.f, 0.f, 0.f, 0.f};

    half4 A0[8], A1[8];
    half8 bX[3], bY[3];
    unsigned aE = aBase + c4 * 512 + r15 * 8;   // ks=0
    unsigned aO = aE + 4096;                    // ks=1

    ISSUE_A(A0, aE);
#pragma unroll
    for (int t = 0; t < 3; ++t)
      if (t < nt) bX[t] = W2f[((tn0 + t) * 13 + 0) * 64 + lane];

#pragma unroll 1
    for (int i = 0; i < 6; ++i) {
      int ks1 = 2 * i + 1, ks2 = 2 * i + 2;
      ISSUE_A(A1, aO);
      aO += 8192;
#pragma unroll
      for (int t = 0; t < 3; ++t)
        if (t < nt) bY[t] = W2f[((tn0 + t) * 13 + ks1) * 64 + lane];
      LGKM(8);
#pragma unroll
      for (int t = 0; t < 3; ++t)
        if (t < nt) {
          half4 blo = LO4(bX[t]), bhi = HI4(bX[t]);
#pragma unroll
          for (int m = 0; m < 4; ++m) {
            MFMA16(A0[m], blo, acc[m][t]);
            MFMA16(A0[4 + m], bhi, acc[m][t]);
          }
        }
      aE += 8192;
      ISSUE_A(A0, aE);
#pragma unroll
      for (int t = 0; t < 3; ++t)
        if (t < nt) bX[t] = W2f[((tn0 + t) * 13 + ks2) * 64 + lane];
      LGKM(8);
#pragma unroll
      for (int t = 0; t < 3; ++t)
        if (t < nt) {
          half4 blo = LO4(bY[t]), bhi = HI4(bY[t]);
#pragma unroll
          for (int m = 0; m < 4; ++m) {
            MFMA16(A1[m], blo, acc[m][t]);
            MFMA16(A1[4 + m], bhi, acc[m][t]);
          }
        }
    }
    LGKM(0);
#pragma unroll
    for (int t = 0; t < 3; ++t)
      if (t < nt) {
        half4 blo = LO4(bX[t]), bhi = HI4(bX[t]);
#pragma unroll
        for (int m = 0; m < 4; ++m) {
          MFMA16(A0[m], blo, acc[m][t]);
          MFMA16(A0[4 + m], bhi, acc[m][t]);
        }
      }

    __syncthreads();  // all a1 reads complete before aliased a2 writes

    // epilogue: relu; col 300 forced to 1.0 (bias for L3); cols 301..319 -> 0
#pragma unroll
    for (int t = 0; t < 3; ++t)
      if (t < nt) {
        int col = (tn0 + t) * 16 + r15;
        int wrel = ((col >> 2) * 4) * 128 + (col & 3) * 32 + 8 * c4;
#pragma unroll
        for (int m = 0; m < 4; ++m) {
          float v0 = fmaxf(acc[m][t][0], 0.f), v1 = fmaxf(acc[m][t][1], 0.f);
          float v2 = fmaxf(acc[m][t][2], 0.f), v3 = fmaxf(acc[m][t][3], 0.f);
          if (col == 300) { v0 = 1.f; v1 = 1.f; v2 = 1.f; v3 = 1.f; }
          half4 hv = pack4(v0, v1, v2, v3);
          *reinterpret_cast<half4*>(reinterpret_cast<char*>(aL) + wrel + m * 128) = hv;
        }
      }
  }
  __syncthreads();

  // ---- phase 3: z3 = a2 @ W3^T + b3, tanh; waves 0..3 (m-tile = w) ----
  if (w < 4) {
    const half8* W3f = reinterpret_cast<const half8*>(ws + 147456);
    floatx4 za = (floatx4){0.f, 0.f, 0.f, 0.f};
    floatx4 zb = (floatx4){0.f, 0.f, 0.f, 0.f};
    unsigned a3 = aBase + w * 128 + c4 * 512 + r15 * 8;
#pragma unroll
    for (int ks = 0; ks < 10; ks += 2) {
      half4 f0, f1, f2, f3;
      TRD(f0, a3, "0");
      TRD(f1, a3, "2048");
      TRD(f2, a3, "4096");
      TRD(f3, a3, "6144");
      half8 w0 = W3f[ks * 64 + lane];
      half8 w1_ = W3f[(ks + 1) * 64 + lane];
      LGKM(0);
      MFMA16(f0, LO4(w0), za);
      MFMA16(f1, HI4(w0), za);
      MFMA16(f2, LO4(w1_), zb);
      MFMA16(f3, HI4(w1_), zb);
      a3 += 8192;
    }
    floatx4 z = za + zb;
    if (r15 < 6) {
#pragma unroll
      for (int r = 0; r < 4; ++r) {
        int orow = 16 * w + 4 * c4 + r;
        z3L[orow * 8 + r15] = fast_tanh(z[r]);
      }
    }
  }
  __syncthreads();

  // ---- phase 4: weighted-L1-ball projection (per row, D=6), threads 0..63 ----
  if (tid < 64) {
    const int row = tid;
    float q[6], wv[6], aq[6], wa[6];
    float S = 0.f;
#pragma unroll
    for (int i = 0; i < 6; ++i) {
      q[i] = z3L[row * 8 + i];
      wv[i] = wvL[row * 6 + i];
      aq[i] = fabsf(q[i]);
      wa[i] = wv[i] * aq[i];
      S += wa[i];
    }
    float lam = 0.f;
    if (!(S <= C_RADIUS)) {
      float rr[6], w2s[6], was[6];
#pragma unroll
      for (int i = 0; i < 6; ++i) {
        rr[i] = (wv[i] > 0.f) ? (aq[i] / fmaxf(wv[i], 1e-30f)) : -__builtin_inff();
        w2s[i] = wv[i] * wv[i];
        was[i] = wa[i];
      }
#pragma unroll
      for (int p = 0; p < 5; ++p)
#pragma unroll
        for (int j2 = 0; j2 < 5; ++j2)
          if (j2 < 5 - p) {
            if (rr[j2] < rr[j2 + 1]) {
              float t0 = rr[j2];  rr[j2] = rr[j2 + 1];  rr[j2 + 1] = t0;
              float t1 = w2s[j2]; w2s[j2] = w2s[j2 + 1]; w2s[j2 + 1] = t1;
              float t2 = was[j2]; was[j2] = was[j2 + 1]; was[j2 + 1] = t2;
            }
          }
      float A = 0.f, Bc = 0.f;
      float lamk[6];
      int kc = 0;
#pragma unroll
      for (int i = 0; i < 6; ++i) {
        A += was[i];
        Bc += w2s[i];
        lamk[i] = (A - C_RADIUS) / fmaxf(Bc, 1e-30f);
        if (rr[i] > lamk[i]) ++kc;
      }
      int idx = kc - 1;
      if (idx < 0) idx = 0;
      float lsel = lamk[0];
#pragma unroll
      for (int i = 1; i < 6; ++i)
        if (i == idx) lsel = lamk[i];
      lam = fmaxf(lsel, 0.f);
    }
#pragma unroll
    for (int i = 0; i < 6; ++i) {
      float x = fmaxf(aq[i] - lam * wv[i], 0.f);
      outL[row * 6 + i] = copysignf(x, q[i]);
    }
  }
  __syncthreads();

  // coalesced float4 store of the 384-float output tile
  if (tid < 96) {
    float4 v = reinterpret_cast<const float4*>(outL)[tid];
    reinterpret_cast<float4*>(out)[blockIdx.x * 96 + tid] = v;
  }
}

extern "C" void kernel_launch(void* const* d_in, const int* in_sizes, int n_in,
                              void* d_out, int out_size, void* d_ws, size_t ws_size,
                              hipStream_t stream) {
  const float* state = (const float*)d_in[0];
  const float* w1 = (const float*)d_in[1];
  const float* b1 = (const float*)d_in[2];
  const float* w2 = (const float*)d_in[3];
  const float* b2 = (const float*)d_in[4];
  const float* w3 = (const float*)d_in[5];
  const float* b3 = (const float*)d_in[6];
  _Float16* ws = (_Float16*)d_ws;
  float* out = (float*)d_out;

  actor_prep<<<75, 256, 0, stream>>>(w1, b1, w2, b2, w3, b3, ws);
  actor_fused<<<4096, 512, 0, stream>>>(state, ws, out);
}

// Round 5
// 97.095 us; speedup vs baseline: 1.9969x; 1.1352x over previous
//
#include <hip/hip_runtime.h>
#include <math.h>

typedef _Float16 half2v __attribute__((ext_vector_type(2)));
typedef __fp16 fp16x2 __attribute__((ext_vector_type(2)));
typedef _Float16 half4 __attribute__((ext_vector_type(4)));
typedef _Float16 half8 __attribute__((ext_vector_type(8)));
typedef float floatx4 __attribute__((ext_vector_type(4)));

#define C_RADIUS 20.0f

// ---------------------------------------------------------------------------
// d_ws layout (units = _Float16). Fragments for mfma_f32_16x16x32_f16:
// lane l holds 8 elems: free-index = l&15, k = 8*(l>>4) + e  (e=0..7).
//   W1f [28 tn][64 lane][8]   @ 0       n=tn*16+(l&15); k<17->w1, k==17->b1, else 0
//   W2f [20 tn][13 ks][64][8] @ 14336   k=32ks+8*(l>>4)+e; k<400->w2, k==400->b2
//   W3f [10 ks][64][8]        @ 147456  n=l&15 (<6); k<300->w3, k==300->b3
// ---------------------------------------------------------------------------

__global__ void actor_prep(const float* __restrict__ w1, const float* __restrict__ b1,
                           const float* __restrict__ w2, const float* __restrict__ b2,
                           const float* __restrict__ w3, const float* __restrict__ b3,
                           _Float16* __restrict__ ws) {
  int gid = blockIdx.x * 256 + threadIdx.x;
  if (gid >= 19072) return;
  half8 hv;
  _Float16* dst;
  if (gid < 1792) {  // W1f
    int l = gid & 63, tn = gid >> 6;
    int n = tn * 16 + (l & 15);
    int kc = 8 * (l >> 4);
#pragma unroll
    for (int e = 0; e < 8; ++e) {
      int k = kc + e;
      float v = 0.f;
      if (n < 400) {
        if (k < 17) v = w1[n * 17 + k];
        else if (k == 17) v = b1[n];
      }
      hv[e] = (_Float16)v;
    }
    dst = ws + gid * 8;
  } else if (gid < 1792 + 16640) {  // W2f
    int g = gid - 1792;
    int l = g & 63, t = g >> 6;     // t = tn*13 + ks
    int ks = t % 13, tn = t / 13;
    int n = tn * 16 + (l & 15);
    int kc = ks * 32 + 8 * (l >> 4);
#pragma unroll
    for (int e = 0; e < 8; ++e) {
      int k = kc + e;
      float v = 0.f;
      if (n < 300) {
        if (k < 400) v = w2[n * 400 + k];
        else if (k == 400) v = b2[n];
      }
      hv[e] = (_Float16)v;
    }
    dst = ws + 14336 + g * 8;
  } else {  // W3f
    int g = gid - 1792 - 16640;
    int l = g & 63, ks = g >> 6;
    int n = l & 15;
    int kc = ks * 32 + 8 * (l >> 4);
#pragma unroll
    for (int e = 0; e < 8; ++e) {
      int k = kc + e;
      float v = 0.f;
      if (n < 6) {
        if (k < 300) v = w3[n * 300 + k];
        else if (k == 300) v = b3[n];
      }
      hv[e] = (_Float16)v;
    }
    dst = ws + 147456 + g * 8;
  }
  *reinterpret_cast<half8*>(dst) = hv;
}

// Row strides (elems): byte-stride/16 odd -> uniform 16B-slot rotation, minimal conflicts.
#define LD1 424   // a1: 400 cols + bias col 400 + zeros ..415 (+8 pad)
#define LD2 328   // a2: 300 cols + bias col 300 + zeros ..319 (+8 pad)
#define LDS_ 40   // stateF: 17 cols + bias col 17 + zeros ..31 (+8 pad)

#define MFMA32(A, B, C) C = __builtin_amdgcn_mfma_f32_16x16x32_f16(A, B, C, 0, 0, 0)

// pack 4 floats -> half4 via two v_cvt_pkrtz_f16_f32
__device__ __forceinline__ half4 pack4(float v0, float v1, float v2, float v3) {
  fp16x2 a = __builtin_amdgcn_cvt_pkrtz(v0, v1);
  fp16x2 b = __builtin_amdgcn_cvt_pkrtz(v2, v3);
  half2v a2 = __builtin_bit_cast(half2v, a);
  half2v b2 = __builtin_bit_cast(half2v, b);
  return __builtin_shufflevector(a2, b2, 0, 1, 2, 3);
}

__device__ __forceinline__ float fast_tanh(float x) {
  float e = __expf(2.0f * x);
  return 1.0f - 2.0f / (e + 1.0f);
}

__global__ __launch_bounds__(512, 4) void actor_fused(const float* __restrict__ state,
                                                      const _Float16* __restrict__ ws,
                                                      float* __restrict__ out) {
  // aL holds a1 [64][LD1] (54272 B); after phase 2 it is reused as a2 [64][LD2].
  __shared__ __align__(16) _Float16 aL[64 * LD1];
  __shared__ __align__(16) _Float16 stateF[64 * LDS_];  // 5120 B
  __shared__ float z3L[64 * 8];
  __shared__ __align__(16) float outL[64 * 6];
  __shared__ float wvL[64 * 6];

  const int tid = threadIdx.x;
  const int lane = tid & 63;
  const int w = tid >> 6;       // 8 waves
  const int r15 = lane & 15;
  const int c4 = lane >> 4;
  const int row0 = blockIdx.x * 64;

  // ---- stage 0 ----
  // stateF: cols 0..16 = state (f16), col 17 = 1.0 bias, cols 18..39 = 0
  for (int i = tid; i < 1088; i += 512) {   // 64*17, coalesced global read
    int r = i / 17, c = i - r * 17;
    stateF[r * LDS_ + c] = (_Float16)state[row0 * 17 + i];
  }
  for (int i = tid; i < 64 * 23; i += 512) {
    int r = i / 23, c = 17 + (i - r * 23);
    stateF[r * LDS_ + c] = (c == 17) ? (_Float16)1.0f : (_Float16)0.0f;
  }
  // a1 cols 400..415: col 400 = 1.0 bias (for layer 2), rest 0
  for (int i = tid; i < 1024; i += 512) {
    int r = i >> 4, c = i & 15;
    aL[r * LD1 + 400 + c] = (c == 0) ? (_Float16)1.0f : (_Float16)0.0f;
  }
  if (tid < 384) {
    int r = tid / 6, c = tid - r * 6;
    wvL[tid] = fabsf(state[(row0 + r) * 17 + 11 + c]);
  }
  __syncthreads();

  // ---- phase 1: a1 = relu(state @ W1^T + b1); swapped operands:
  //      mfma(Wfrag, actfrag) -> C[col=act-row][row=n] ----
  {
    half8 S[4];
#pragma unroll
    for (int m = 0; m < 4; ++m)
      S[m] = *reinterpret_cast<const half8*>(&stateF[(16 * m + r15) * LDS_ + 8 * c4]);
    const half8* W1f = reinterpret_cast<const half8*>(ws);
#pragma unroll
    for (int t = 0; t < 4; ++t) {
      int tn = w + 8 * t;
      if (tn < 25) {
        half8 aW = W1f[tn * 64 + lane];
        floatx4 acc[4];
#pragma unroll
        for (int m = 0; m < 4; ++m) {
          acc[m] = (floatx4){0.f, 0.f, 0.f, 0.f};
          MFMA32(aW, S[m], acc[m]);
        }
        int n0 = tn * 16 + 4 * c4;   // lane's 4 output cols (n), all < 400
#pragma unroll
        for (int m = 0; m < 4; ++m) {
          half4 hv = pack4(fmaxf(acc[m][0], 0.f), fmaxf(acc[m][1], 0.f),
                           fmaxf(acc[m][2], 0.f), fmaxf(acc[m][3], 0.f));
          *reinterpret_cast<half4*>(&aL[(16 * m + r15) * LD1 + n0]) = hv;
        }
      }
    }
  }
  __syncthreads();

  // ---- phase 2: a2 = relu(a1 @ W2^T + b2); n-tiles {3,3,3,3,2,2,2,2} ----
  {
    const half8* W2f = reinterpret_cast<const half8*>(ws + 14336);
    const int nt = (w < 4) ? 3 : 2;
    const int tn0 = (w < 4) ? (w * 3) : (12 + (w - 4) * 2);
    floatx4 acc[4][3];
#pragma unroll
    for (int m = 0; m < 4; ++m)
#pragma unroll
      for (int t = 0; t < 3; ++t) acc[m][t] = (floatx4){0.f, 0.f, 0.f, 0.f};

    half8 bX[3], bY[3];
#pragma unroll
    for (int t = 0; t < 3; ++t)
      if (t < nt) bX[t] = W2f[((tn0 + t) * 13 + 0) * 64 + lane];

#pragma unroll 1
    for (int ks = 0; ks < 13; ++ks) {
      if (ks < 12) {
#pragma unroll
        for (int t = 0; t < 3; ++t)
          if (t < nt) bY[t] = W2f[((tn0 + t) * 13 + ks + 1) * 64 + lane];
      }
      half8 F[4];
#pragma unroll
      for (int m = 0; m < 4; ++m)
        F[m] = *reinterpret_cast<const half8*>(&aL[(16 * m + r15) * LD1 + ks * 32 + 8 * c4]);
#pragma unroll
      for (int t = 0; t < 3; ++t)
        if (t < nt)
#pragma unroll
          for (int m = 0; m < 4; ++m)
            MFMA32(bX[t], F[m], acc[m][t]);
#pragma unroll
      for (int t = 0; t < 3; ++t) bX[t] = bY[t];
    }
    __syncthreads();  // all a1 reads complete before aliased a2 writes

    // epilogue: relu; n==300 forced to 1.0 (bias for L3); n 301..319 are 0
#pragma unroll
    for (int t = 0; t < 3; ++t)
      if (t < nt) {
        int n0 = (tn0 + t) * 16 + 4 * c4;
#pragma unroll
        for (int m = 0; m < 4; ++m) {
          float v0 = fmaxf(acc[m][t][0], 0.f), v1 = fmaxf(acc[m][t][1], 0.f);
          float v2 = fmaxf(acc[m][t][2], 0.f), v3 = fmaxf(acc[m][t][3], 0.f);
          if (n0 == 300) v0 = 1.0f;
          half4 hv = pack4(v0, v1, v2, v3);
          *reinterpret_cast<half4*>(&aL[(16 * m + r15) * LD2 + n0]) = hv;
        }
      }
  }
  __syncthreads();

  // ---- phase 3: z3 = a2 @ W3^T + b3, tanh; waves 0..3 (m-tile = w) ----
  if (w < 4) {
    const half8* W3f = reinterpret_cast<const half8*>(ws + 147456);
    floatx4 za = (floatx4){0.f, 0.f, 0.f, 0.f};
    floatx4 zb = (floatx4){0.f, 0.f, 0.f, 0.f};
    const int row = 16 * w + r15;
#pragma unroll
    for (int ks = 0; ks < 10; ks += 2) {
      half8 F0 = *reinterpret_cast<const half8*>(&aL[row * LD2 + ks * 32 + 8 * c4]);
      half8 F1 = *reinterpret_cast<const half8*>(&aL[row * LD2 + (ks + 1) * 32 + 8 * c4]);
      MFMA32(W3f[ks * 64 + lane], F0, za);
      MFMA32(W3f[(ks + 1) * 64 + lane], F1, zb);
    }
    floatx4 z = za + zb;
    // lane (c4,r15): n = 4*c4 + j, act-row = row; only n<6 valid
    if (c4 == 0) {
#pragma unroll
      for (int j = 0; j < 4; ++j) z3L[row * 8 + j] = fast_tanh(z[j]);
    } else if (c4 == 1) {
      z3L[row * 8 + 4] = fast_tanh(z[0]);
      z3L[row * 8 + 5] = fast_tanh(z[1]);
    }
  }
  __syncthreads();

  // ---- phase 4: weighted-L1-ball projection (per row, D=6), threads 0..63 ----
  if (tid < 64) {
    const int row = tid;
    float q[6], wv[6], aq[6], wa[6];
    float S = 0.f;
#pragma unroll
    for (int i = 0; i < 6; ++i) {
      q[i] = z3L[row * 8 + i];
      wv[i] = wvL[row * 6 + i];
      aq[i] = fabsf(q[i]);
      wa[i] = wv[i] * aq[i];
      S += wa[i];
    }
    float lam = 0.f;
    if (!(S <= C_RADIUS)) {
      float rr[6], w2s[6], was[6];
#pragma unroll
      for (int i = 0; i < 6; ++i) {
        rr[i] = (wv[i] > 0.f) ? (aq[i] / fmaxf(wv[i], 1e-30f)) : -__builtin_inff();
        w2s[i] = wv[i] * wv[i];
        was[i] = wa[i];
      }
#pragma unroll
      for (int p = 0; p < 5; ++p)
#pragma unroll
        for (int j2 = 0; j2 < 5; ++j2)
          if (j2 < 5 - p) {
            if (rr[j2] < rr[j2 + 1]) {
              float t0 = rr[j2];  rr[j2] = rr[j2 + 1];  rr[j2 + 1] = t0;
              float t1 = w2s[j2]; w2s[j2] = w2s[j2 + 1]; w2s[j2 + 1] = t1;
              float t2 = was[j2]; was[j2] = was[j2 + 1]; was[j2 + 1] = t2;
            }
          }
      float A = 0.f, Bc = 0.f;
      float lamk[6];
      int kc = 0;
#pragma unroll
      for (int i = 0; i < 6; ++i) {
        A += was[i];
        Bc += w2s[i];
        lamk[i] = (A - C_RADIUS) / fmaxf(Bc, 1e-30f);
        if (rr[i] > lamk[i]) ++kc;
      }
      int idx = kc - 1;
      if (idx < 0) idx = 0;
      float lsel = lamk[0];
#pragma unroll
      for (int i = 1; i < 6; ++i)
        if (i == idx) lsel = lamk[i];
      lam = fmaxf(lsel, 0.f);
    }
#pragma unroll
    for (int i = 0; i < 6; ++i) {
      float x = fmaxf(aq[i] - lam * wv[i], 0.f);
      outL[row * 6 + i] = copysignf(x, q[i]);
    }
  }
  __syncthreads();

  // coalesced float4 store of the 384-float output tile
  if (tid < 96) {
    float4 v = reinterpret_cast<const float4*>(outL)[tid];
    reinterpret_cast<float4*>(out)[blockIdx.x * 96 + tid] = v;
  }
}

extern "C" void kernel_launch(void* const* d_in, const int* in_sizes, int n_in,
                              void* d_out, int out_size, void* d_ws, size_t ws_size,
                              hipStream_t stream) {
  const float* state = (const float*)d_in[0];
  const float* w1 = (const float*)d_in[1];
  const float* b1 = (const float*)d_in[2];
  const float* w2 = (const float*)d_in[3];
  const float* b2 = (const float*)d_in[4];
  const float* w3 = (const float*)d_in[5];
  const float* b3 = (const float*)d_in[6];
  _Float16* ws = (_Float16*)d_ws;
  float* out = (float*)d_out;

  actor_prep<<<75, 256, 0, stream>>>(w1, b1, w2, b2, w3, b3, ws);
  actor_fused<<<4096, 512, 0, stream>>>(state, ws, out);
}